// Round 10
// baseline (590.818 us; speedup 1.0000x reference)
//
#include <hip/hip_runtime.h>
#include <hip/hip_bf16.h>

#define NPTS 600000
#define NKEYS (1 << 22)          // 2 * 128^3 compact key space
#define CHUNK 4096
#define NPART (NKEYS / CHUNK)    // 1024

typedef unsigned int u32;
typedef unsigned short u16;
typedef __attribute__((ext_vector_type(8))) short short8;   // 8 bf16 = 4 VGPRs
typedef __attribute__((ext_vector_type(4))) float f32x4;

__device__ __forceinline__ u16 f2bf(float x) {
  union { float f; u32 u; } c; c.f = x;
  u32 r = c.u + 0x7fffu + ((c.u >> 16) & 1u);   // RNE, inputs finite
  return (u16)(r >> 16);
}

// ---- K0a: fold BN into alpha/beta -------------------------------------------
__global__ void k0a_bn(const float* __restrict__ s, const float* __restrict__ b,
                       const float* __restrict__ m, const float* __restrict__ v,
                       float* __restrict__ ab) {
  int c = threadIdx.x;   // 64 threads
  float a = s[c] * rsqrtf(v[c] + 1e-5f);
  ab[c] = a;
  ab[64 + c] = b[c] - m[c] * a;
}

// ---- K0b: W[27][cin][cout] f32 -> Wt[27][cout][cin] bf16 --------------------
__global__ void k0b_wt(const float* __restrict__ W, u16* __restrict__ Wt) {
  int e = blockIdx.x * 256 + threadIdx.x;
  if (e >= 27 * 4096) return;
  int k = e >> 12, rem = e & 4095, cin = rem >> 6, cout = rem & 63;
  Wt[(k << 12) + (cout << 6) + cin] = f2bf(W[e]);
}

// ---- K1: compact keys + per-voxel point counts ------------------------------
__global__ void k1_keys(const int* __restrict__ coords, int* __restrict__ keys,
                        u32* __restrict__ lut) {
  int i = blockIdx.x * 256 + threadIdx.x;
  if (i >= NPTS) return;
  int4 c4 = *(const int4*)(coords + i * 4);
  int k = (c4.w << 21) | ((c4.x >> 1) << 14) | ((c4.y >> 1) << 7) | (c4.z >> 1);
  keys[i] = k;
  atomicAdd(&lut[k], 1u);   // count points per voxel (~600k atomics total)
}

// ---- K2a: per-chunk occupied-voxel counts -----------------------------------
__global__ void k2a_part(const u32* __restrict__ lut, u32* __restrict__ partials) {
  __shared__ u32 sd[256];
  int blk = blockIdx.x, t = threadIdx.x;
  const u32* p = lut + blk * CHUNK;
  u32 s = 0;
  for (int j = t; j < CHUNK; j += 256) s += (p[j] != 0u);
  sd[t] = s; __syncthreads();
  for (int o = 128; o > 0; o >>= 1) { if (t < o) sd[t] += sd[t + o]; __syncthreads(); }
  if (t == 0) partials[blk] = sd[0];
}

// ---- K2b: scan the 1024 partials (exclusive) + total U ----------------------
__global__ void k2b_top(u32* __restrict__ partials) {
  __shared__ u32 sh[NPART];
  int t = threadIdx.x;   // 1024 threads
  u32 x = partials[t];
  sh[t] = x; __syncthreads();
  for (int off = 1; off < NPART; off <<= 1) {
    u32 add = (t >= off) ? sh[t - off] : 0u;
    __syncthreads();
    sh[t] += add;
    __syncthreads();
  }
  partials[t] = sh[t] - x;                       // exclusive
  if (t == NPART - 1) partials[NPART] = sh[t];   // total unique count U
}

// ---- K2c: fill lut ((rank+1)|multi<<31 or 0), r2k, zero multi f32 rows ------
__global__ void k2c_fill(u32* __restrict__ lut, const u32* __restrict__ partials,
                         int* __restrict__ r2k, float* __restrict__ fds32) {
  __shared__ u32 tsum[256];
  int blk = blockIdx.x, t = threadIdx.x;
  int base = blk * CHUNK + t * 16;
  u32 loc[16]; u32 s = 0;
#pragma unroll
  for (int j = 0; j < 16; j++) { loc[j] = lut[base + j]; s += (loc[j] != 0u); }
  tsum[t] = s; __syncthreads();
  for (int off = 1; off < 256; off <<= 1) {
    u32 add = (t >= off) ? tsum[t - off] : 0u;
    __syncthreads();
    tsum[t] += add;
    __syncthreads();
  }
  u32 rank = partials[blk] + tsum[t] - s;   // exclusive rank for first elem
#pragma unroll
  for (int j = 0; j < 16; j++) {
    if (loc[j]) {
      u32 flag = (loc[j] > 1u) ? 0x80000000u : 0u;
      lut[base + j] = (rank + 1u) | flag;
      r2k[rank] = base + j;
      if (flag) {   // zero the f32 accumulation row for multi-point voxels
        float4 z = {0.f, 0.f, 0.f, 0.f};
        float* d = fds32 + ((size_t)rank << 6);
#pragma unroll
        for (int c = 0; c < 16; c++) *(float4*)(d + c * 4) = z;
      }
      rank++;
    } else lut[base + j] = 0u;
  }
}

// ---- K3: fused segment-sum: singles -> bf16 direct, multis -> f32 atomics ---
__global__ void k3_seg(const float* __restrict__ feats, const int* __restrict__ keys,
                       const u32* __restrict__ lut, float* __restrict__ fds32,
                       u16* __restrict__ fdsb) {
  int idx = blockIdx.x * 256 + threadIdx.x;   // NPTS*16 threads, 4 ch each
  if (idx >= NPTS * 16) return;
  int i = idx >> 4, q = (idx & 15) << 2;
  u32 lv = lut[keys[i]];
  u32 r = (lv & 0x7fffffffu) - 1u;
  float4 v = *(const float4*)(feats + (size_t)i * 64 + q);
  if (lv >> 31) {               // ~13% of points: shared voxel, accumulate f32
    float* dst = fds32 + ((size_t)r << 6) + q;
    atomicAdd(dst + 0, v.x); atomicAdd(dst + 1, v.y);
    atomicAdd(dst + 2, v.z); atomicAdd(dst + 3, v.w);
  } else {                      // ~87%: sole occupant, convert + plain store
    ushort4 o;
    o.x = f2bf(v.x); o.y = f2bf(v.y); o.z = f2bf(v.z); o.w = f2bf(v.w);
    *(ushort4*)(fdsb + ((size_t)r << 6) + q) = o;
  }
}

// ---- K3b: convert only multi-voxel rows f32 -> bf16 -------------------------
__global__ void k3b_fix(const int* __restrict__ r2k, const u32* __restrict__ lut,
                        const u32* __restrict__ pU,
                        const float* __restrict__ fds32, u16* __restrict__ fdsb) {
  int idx = blockIdx.x * 256 + threadIdx.x;   // NPTS*4 threads, 16 ch each
  int r = idx >> 2;
  if (r >= (int)(*pU)) return;
  u32 lv = lut[r2k[r]];
  if (!(lv >> 31)) return;
  int q = (idx & 3) << 4;
  const float* src = fds32 + ((size_t)r << 6) + q;
  u16* dst = fdsb + ((size_t)r << 6) + q;
#pragma unroll
  for (int j = 0; j < 4; j++) {
    float4 v = *(const float4*)(src + j * 4);
    ushort4 o;
    o.x = f2bf(v.x); o.y = f2bf(v.y); o.z = f2bf(v.z); o.w = f2bf(v.w);
    *(ushort4*)(dst + j * 4) = o;
  }
}

// ---- K4: async producer/consumer gather-GEMM + BN/ReLU ----------------------
// Block = 320 thr (5 waves), 64 output rows. Raw s_barrier (NO vmcnt drain):
// producer at iter k (a) ds_writes tile k+1 from regs (compiler's auto-wait
// covers exactly the loads issued one iter ago), (b) THEN issues the 8 exec-
// masked loads for tile k+2 (stay in flight across the barrier), (c) probes
// lut for tile k+4 (lvr ring 4). Tile t: probed at t-4, reg-loaded at t-2,
// ds_written at t-1 (slot t&1), consumed at t. Every load has a full
// iteration to land instead of being drained by __syncthreads (m97 stall).
// Consumers (waves 1-4): one 16-cout block each; LDS reads use the same
// bank-rotation as the writes (measured 0 conflicts).
__global__ __launch_bounds__(320) void k4_conv(
    const u32* __restrict__ lut, const int* __restrict__ r2k,
    const u16* __restrict__ fdsb, const u16* __restrict__ Wt,
    const u32* __restrict__ pU, const float* __restrict__ ab,
    float* __restrict__ out) {
  __shared__ __align__(16) char ldsA[2][8192];   // ring: 64 rows x 128B
  const u32 U = *pU;
  int tid = threadIdx.x;
  int w = tid >> 6, l = tid & 63;
  // XCD-bijective swizzle (grid multiple of 8): rank-contiguous chunks per XCD.
  int bid = blockIdx.x;
  int cpx = (int)gridDim.x >> 3;
  int swz = (bid & 7) * cpx + (bid >> 3);
  int rbase = swz * 64;

  // ---- producer state (wave 0): lane l owns output row rbase + l ----
  int key = -1, x = 0, y = 0, z = 0;
  if (w == 0) {
    int r = rbase + l;
    key = ((u32)r < U) ? r2k[r] : -1;
    z = key & 127; y = (key >> 7) & 127; x = (key >> 14) & 127;
  }
  u32 lvr[4];          // lut ring: tile t probed at iter t-4
  short8 rg[2][8];     // reg staging: tile t loaded at iter t-2, parity t&1
  const short8 z8 = {0, 0, 0, 0, 0, 0, 0, 0};

  // branchless lut probe for tile T (sentinel entry NKEYS == 0 for OOB)
#define PROBE(T) { \
    const int dx_ = (T) / 9 - 1, dy_ = ((T) / 3) % 3 - 1, dz_ = (T) % 3 - 1; \
    int nx_ = x + dx_, ny_ = y + dy_, nz_ = z + dz_; \
    bool ok_ = (key >= 0) & ((u32)nx_ < 128u) & ((u32)ny_ < 128u) & ((u32)nz_ < 128u); \
    int a_ = ok_ ? (key + dx_ * 16384 + dy_ * 128 + dz_) : NKEYS; \
    lvr[(T) & 3] = lut[a_]; }

  // exec-masked reg load of tile T (zeros on miss lanes; ~13% hit rate)
#define LOADRG(T) { \
    u32 lv_ = lvr[(T) & 3]; \
    _Pragma("unroll") for (int j = 0; j < 8; j++) rg[(T) & 1][j] = z8; \
    if (lv_) { \
      const u16* fr_ = fdsb + ((size_t)((lv_ & 0x7fffffffu) - 1u) << 6); \
      _Pragma("unroll") for (int j = 0; j < 8; j++) \
        rg[(T) & 1][j] = *(const short8*)(fr_ + j * 8); } }

  // LDS write of tile T (bank-rotated by row&7; compiler inserts the counted
  // vmcnt wait for exactly tile T's loads here)
#define DSW(T) { \
    char* dst_ = &ldsA[(T) & 1][l * 128]; \
    int r7_ = l & 7; \
    _Pragma("unroll") for (int j = 0; j < 8; j++) \
      *(short8*)(dst_ + (((j + r7_) & 7) << 4)) = rg[(T) & 1][j]; }

  // ---- consumer state (waves 1-4): one 16-cout block each ----
  int ct = w - 1;
  int col = l & 15, kg = l >> 4;
  f32x4 acc[4] = {};   // 4 row-tiles of 16

  // prologue: probe tiles 0-3; tile 0 -> LDS slot 0; tile 1 loads in flight
  if (w == 0) {
    PROBE(0) PROBE(1) PROBE(2) PROBE(3)
    LOADRG(0)
    DSW(0)
    LOADRG(1)          // stays in flight across the raw barrier
  }
  asm volatile("" ::: "memory");
  asm volatile("s_waitcnt lgkmcnt(0)" ::: "memory");
  __builtin_amdgcn_s_barrier();
  asm volatile("" ::: "memory");

#pragma unroll
  for (int k = 0; k < 27; k++) {
    if (w == 0) {
      if (k + 1 < 27) DSW(k + 1)       // waits (counted) on loads from iter k-1
      if (k + 2 < 27) LOADRG(k + 2)    // fresh loads, cross the barrier
      if (k + 4 < 27) PROBE(k + 4)
    } else {
      const u16* wk = Wt + (k << 12) + (((ct << 4) + col) << 6) + (kg << 3);
      short8 b0 = *(const short8*)(wk);
      short8 b1 = *(const short8*)(wk + 32);
      const char* slab = &ldsA[k & 1][0];
#pragma unroll
      for (int rt = 0; rt < 4; rt++) {
        int row = (rt << 4) + col;
        const char* rp = slab + row * 128;
        int r7 = row & 7;
        short8 a0 = *(const short8*)(rp + (((kg + r7) & 7) << 4));
        short8 a1 = *(const short8*)(rp + (((kg + 4 + r7) & 7) << 4));
        acc[rt] = __builtin_amdgcn_mfma_f32_16x16x32_bf16(a0, b0, acc[rt], 0, 0, 0);
        acc[rt] = __builtin_amdgcn_mfma_f32_16x16x32_bf16(a1, b1, acc[rt], 0, 0, 0);
      }
    }
    asm volatile("" ::: "memory");
    asm volatile("s_waitcnt lgkmcnt(0)" ::: "memory");
    __builtin_amdgcn_s_barrier();
    asm volatile("" ::: "memory");
  }
#undef PROBE
#undef LOADRG
#undef DSW

  // epilogue (consumers): BN + ReLU, zeros for invalid (r >= U) rows
  if (w > 0) {
    int c = (ct << 4) | col;
    float al = ab[c], be = ab[64 + c];
#pragma unroll
    for (int rt = 0; rt < 4; rt++) {
#pragma unroll
      for (int i = 0; i < 4; i++) {
        int r = rbase + (rt << 4) + (kg << 2) + i;
        if (r >= NPTS) continue;
        bool valid = ((u32)r < U);
        float vv = 0.f;
        if (valid) {
          vv = fmaf(acc[rt][i], al, be);
          vv = vv > 0.f ? vv : 0.f;
        }
        out[((size_t)r << 6) + c] = vv;
      }
    }
  }
}

extern "C" void kernel_launch(void* const* d_in, const int* in_sizes, int n_in,
                              void* d_out, int out_size, void* d_ws, size_t ws_size,
                              hipStream_t stream) {
  const int*   coords = (const int*)d_in[0];
  const float* feats  = (const float*)d_in[1];
  const float* W      = (const float*)d_in[2];
  const float* bns    = (const float*)d_in[3];
  const float* bnb    = (const float*)d_in[4];
  const float* bnm    = (const float*)d_in[5];
  const float* bnv    = (const float*)d_in[6];
  float* out = (float*)d_out;

  char* ws = (char*)d_ws;
  size_t off = 0;
  auto alloc = [&](size_t bytes) -> void* {
    void* p = ws + off;
    off += (bytes + 255) & ~(size_t)255;
    return p;
  };
  u32* lut      = (u32*)alloc((size_t)(NKEYS + 1) * 4);  // +1 zero sentinel
  u32* partials = (u32*)alloc((NPART + 8) * 4);
  int* keys     = (int*)alloc((size_t)NPTS * 4);
  int* r2k      = (int*)alloc((size_t)NPTS * 4);
  u16* fdsb     = (u16*)alloc((size_t)(NPTS + 1) * 64 * 2);
  u16* Wt       = (u16*)alloc((size_t)27 * 4096 * 2);
  float* ab     = (float*)alloc(128 * 4);
  (void)ws_size; (void)out_size; (void)n_in; (void)in_sizes;

  float* fds32 = out;   // d_out doubles as f32 staging for multi-point voxels

  hipMemsetAsync(lut, 0, (size_t)(NKEYS + 1) * 4, stream);

  k0a_bn<<<1, 64, 0, stream>>>(bns, bnb, bnm, bnv, ab);
  k0b_wt<<<(27 * 4096 + 255) / 256, 256, 0, stream>>>(W, Wt);
  k1_keys<<<(NPTS + 255) / 256, 256, 0, stream>>>(coords, keys, lut);
  k2a_part<<<NPART, 256, 0, stream>>>(lut, partials);
  k2b_top<<<1, NPART, 0, stream>>>(partials);
  k2c_fill<<<NPART, 256, 0, stream>>>(lut, partials, r2k, fds32);
  k3_seg<<<(NPTS * 16 + 255) / 256, 256, 0, stream>>>(feats, keys, lut, fds32, fdsb);
  k3b_fix<<<(NPTS * 4 + 255) / 256, 256, 0, stream>>>(r2k, lut, partials + NPART, fds32, fdsb);
  // 64 rows per block; 9376 blocks (multiple of 8 for the XCD swizzle)
  k4_conv<<<(NPTS + 63) / 64, 320, 0, stream>>>(lut, r2k, fdsb, Wt,
                                                partials + NPART, ab, out);
}

// Round 11
// 557.136 us; speedup vs baseline: 1.0605x; 1.0605x over previous
//
#include <hip/hip_runtime.h>
#include <hip/hip_bf16.h>

#define NPTS 600000
#define NKEYS (1 << 22)          // 2 * 128^3 compact key space
#define CHUNK 4096
#define NPART (NKEYS / CHUNK)    // 1024

typedef unsigned int u32;
typedef unsigned short u16;
typedef __attribute__((ext_vector_type(8))) short short8;   // 8 bf16 = 4 VGPRs
typedef __attribute__((ext_vector_type(4))) float f32x4;

__device__ __forceinline__ u16 f2bf(float x) {
  union { float f; u32 u; } c; c.f = x;
  u32 r = c.u + 0x7fffu + ((c.u >> 16) & 1u);   // RNE, inputs finite
  return (u16)(r >> 16);
}

// ---- K0a: fold BN into alpha/beta -------------------------------------------
__global__ void k0a_bn(const float* __restrict__ s, const float* __restrict__ b,
                       const float* __restrict__ m, const float* __restrict__ v,
                       float* __restrict__ ab) {
  int c = threadIdx.x;   // 64 threads
  float a = s[c] * rsqrtf(v[c] + 1e-5f);
  ab[c] = a;
  ab[64 + c] = b[c] - m[c] * a;
}

// ---- K0b: W[27][cin][cout] f32 -> Wt[27][cout][cin] bf16 --------------------
__global__ void k0b_wt(const float* __restrict__ W, u16* __restrict__ Wt) {
  int e = blockIdx.x * 256 + threadIdx.x;
  if (e >= 27 * 4096) return;
  int k = e >> 12, rem = e & 4095, cin = rem >> 6, cout = rem & 63;
  Wt[(k << 12) + (cout << 6) + cin] = f2bf(W[e]);
}

// ---- K1: compact keys + per-voxel point counts ------------------------------
__global__ void k1_keys(const int* __restrict__ coords, int* __restrict__ keys,
                        u32* __restrict__ lut) {
  int i = blockIdx.x * 256 + threadIdx.x;
  if (i >= NPTS) return;
  int4 c4 = *(const int4*)(coords + i * 4);
  int k = (c4.w << 21) | ((c4.x >> 1) << 14) | ((c4.y >> 1) << 7) | (c4.z >> 1);
  keys[i] = k;
  atomicAdd(&lut[k], 1u);   // count points per voxel (~600k atomics total)
}

// ---- K2a: per-chunk occupied-voxel counts -----------------------------------
__global__ void k2a_part(const u32* __restrict__ lut, u32* __restrict__ partials) {
  __shared__ u32 sd[256];
  int blk = blockIdx.x, t = threadIdx.x;
  const u32* p = lut + blk * CHUNK;
  u32 s = 0;
  for (int j = t; j < CHUNK; j += 256) s += (p[j] != 0u);
  sd[t] = s; __syncthreads();
  for (int o = 128; o > 0; o >>= 1) { if (t < o) sd[t] += sd[t + o]; __syncthreads(); }
  if (t == 0) partials[blk] = sd[0];
}

// ---- K2b: scan the 1024 partials (exclusive) + total U ----------------------
__global__ void k2b_top(u32* __restrict__ partials) {
  __shared__ u32 sh[NPART];
  int t = threadIdx.x;   // 1024 threads
  u32 x = partials[t];
  sh[t] = x; __syncthreads();
  for (int off = 1; off < NPART; off <<= 1) {
    u32 add = (t >= off) ? sh[t - off] : 0u;
    __syncthreads();
    sh[t] += add;
    __syncthreads();
  }
  partials[t] = sh[t] - x;                       // exclusive
  if (t == NPART - 1) partials[NPART] = sh[t];   // total unique count U
}

// ---- K2c: fill lut ((rank+1)|multi<<31 or 0), r2k, zero multi f32 rows ------
__global__ void k2c_fill(u32* __restrict__ lut, const u32* __restrict__ partials,
                         int* __restrict__ r2k, float* __restrict__ fds32) {
  __shared__ u32 tsum[256];
  int blk = blockIdx.x, t = threadIdx.x;
  int base = blk * CHUNK + t * 16;
  u32 loc[16]; u32 s = 0;
#pragma unroll
  for (int j = 0; j < 16; j++) { loc[j] = lut[base + j]; s += (loc[j] != 0u); }
  tsum[t] = s; __syncthreads();
  for (int off = 1; off < 256; off <<= 1) {
    u32 add = (t >= off) ? tsum[t - off] : 0u;
    __syncthreads();
    tsum[t] += add;
    __syncthreads();
  }
  u32 rank = partials[blk] + tsum[t] - s;   // exclusive rank for first elem
#pragma unroll
  for (int j = 0; j < 16; j++) {
    if (loc[j]) {
      u32 flag = (loc[j] > 1u) ? 0x80000000u : 0u;
      lut[base + j] = (rank + 1u) | flag;
      r2k[rank] = base + j;
      if (flag) {   // zero the f32 accumulation row for multi-point voxels
        float4 z = {0.f, 0.f, 0.f, 0.f};
        float* d = fds32 + ((size_t)rank << 6);
#pragma unroll
        for (int c = 0; c < 16; c++) *(float4*)(d + c * 4) = z;
      }
      rank++;
    } else lut[base + j] = 0u;
  }
}

// ---- K3: fused segment-sum: singles -> bf16 direct, multis -> f32 atomics ---
__global__ void k3_seg(const float* __restrict__ feats, const int* __restrict__ keys,
                       const u32* __restrict__ lut, float* __restrict__ fds32,
                       u16* __restrict__ fdsb) {
  int idx = blockIdx.x * 256 + threadIdx.x;   // NPTS*16 threads, 4 ch each
  if (idx >= NPTS * 16) return;
  int i = idx >> 4, q = (idx & 15) << 2;
  u32 lv = lut[keys[i]];
  u32 r = (lv & 0x7fffffffu) - 1u;
  float4 v = *(const float4*)(feats + (size_t)i * 64 + q);
  if (lv >> 31) {               // ~13% of points: shared voxel, accumulate f32
    float* dst = fds32 + ((size_t)r << 6) + q;
    atomicAdd(dst + 0, v.x); atomicAdd(dst + 1, v.y);
    atomicAdd(dst + 2, v.z); atomicAdd(dst + 3, v.w);
  } else {                      // ~87%: sole occupant, convert + plain store
    ushort4 o;
    o.x = f2bf(v.x); o.y = f2bf(v.y); o.z = f2bf(v.z); o.w = f2bf(v.w);
    *(ushort4*)(fdsb + ((size_t)r << 6) + q) = o;
  }
}

// ---- K3b: convert only multi-voxel rows f32 -> bf16 -------------------------
__global__ void k3b_fix(const int* __restrict__ r2k, const u32* __restrict__ lut,
                        const u32* __restrict__ pU,
                        const float* __restrict__ fds32, u16* __restrict__ fdsb) {
  int idx = blockIdx.x * 256 + threadIdx.x;   // NPTS*4 threads, 16 ch each
  int r = idx >> 2;
  if (r >= (int)(*pU)) return;
  u32 lv = lut[r2k[r]];
  if (!(lv >> 31)) return;
  int q = (idx & 3) << 4;
  const float* src = fds32 + ((size_t)r << 6) + q;
  u16* dst = fdsb + ((size_t)r << 6) + q;
#pragma unroll
  for (int j = 0; j < 4; j++) {
    float4 v = *(const float4*)(src + j * 4);
    ushort4 o;
    o.x = f2bf(v.x); o.y = f2bf(v.y); o.z = f2bf(v.z); o.w = f2bf(v.w);
    *(ushort4*)(dst + j * 4) = o;
  }
}

// ---- K4: deep-async producer/consumer gather-GEMM (m201 pattern) ------------
// Block = 320 thr (5 waves), 64 output rows. Producer (w0): depth-3 tile
// pipeline of branchless global_load_lds (zero VGPR cost per outstanding
// load; miss lanes read the shared zero row -> fixed 8 instr/tile so vmcnt
// is countable). Per iter k: issue GLD(k+3) + PROBE(k+6), then
// s_waitcnt vmcnt(N) keeping 2 batches (18 ops) in flight, then RAW
// s_barrier -- loads cross barriers (m201-verified). Tile t: probed iter
// t-6, gload'ed iter t-3, retired by barrier@t-1, read iter t, slot t%5
// reused for t+5 issued iter t+2 (safe gap). LDS [chunk][row] layout =
// gload_lds hardware pattern (R8-verified correct, 0 bank conflicts).
// Consumers (w1-4): one 16-cout block each, compiler-managed counted waits.
__global__ __launch_bounds__(320) void k4_conv(
    const u32* __restrict__ lut, const int* __restrict__ r2k,
    const u16* __restrict__ fdsb, const u16* __restrict__ Wt,
    const u32* __restrict__ pU, const float* __restrict__ ab,
    float* __restrict__ out) {
  __shared__ __align__(16) char ldsA[5][8192];   // ring: [chunk 0..7][row 0..63] x 16B
  const u32 U = *pU;
  int tid = threadIdx.x;
  int w = tid >> 6, l = tid & 63;
  // XCD-bijective swizzle (grid multiple of 8): rank-contiguous chunks per XCD.
  int bid = blockIdx.x;
  int cpx = (int)gridDim.x >> 3;
  int swz = (bid & 7) * cpx + (bid >> 3);
  int rbase = swz * 64;

  // ---- producer state (wave 0): lane l owns output row rbase + l ----
  int key = -1, x = 0, y = 0, z = 0;
  if (w == 0) {
    int r = rbase + l;
    key = ((u32)r < U) ? r2k[r] : -1;
    z = key & 127; y = (key >> 7) & 127; x = (key >> 14) & 127;
  }
  u32 lvr[4];   // probe ring: P(T) issued iter T-6, consumed (address) iter T-3

#define PROBE(T) { \
    const int dx_ = (T) / 9 - 1, dy_ = ((T) / 3) % 3 - 1, dz_ = (T) % 3 - 1; \
    int nx_ = x + dx_, ny_ = y + dy_, nz_ = z + dz_; \
    bool ok_ = (key >= 0) & ((u32)nx_ < 128u) & ((u32)ny_ < 128u) & ((u32)nz_ < 128u); \
    int a_ = ok_ ? (key + dx_ * 16384 + dy_ * 128 + dz_) : NKEYS; \
    lvr[(T) & 3] = lut[a_]; }

  // branchless direct global->LDS gather (8 x 16B); miss -> zero row NPTS
#define GLD(T) { \
    u32 lv_ = lvr[(T) & 3]; \
    u32 row_ = lv_ ? ((lv_ & 0x7fffffffu) - 1u) : (u32)NPTS; \
    const char* fr_ = (const char*)(fdsb + ((size_t)row_ << 6)); \
    char* sl_ = &ldsA[(T) % 5][0]; \
    __builtin_amdgcn_global_load_lds((const __attribute__((address_space(1))) void*)(fr_ +   0), (__attribute__((address_space(3))) void*)(sl_ +    0), 16, 0, 0); \
    __builtin_amdgcn_global_load_lds((const __attribute__((address_space(1))) void*)(fr_ +  16), (__attribute__((address_space(3))) void*)(sl_ + 1024), 16, 0, 0); \
    __builtin_amdgcn_global_load_lds((const __attribute__((address_space(1))) void*)(fr_ +  32), (__attribute__((address_space(3))) void*)(sl_ + 2048), 16, 0, 0); \
    __builtin_amdgcn_global_load_lds((const __attribute__((address_space(1))) void*)(fr_ +  48), (__attribute__((address_space(3))) void*)(sl_ + 3072), 16, 0, 0); \
    __builtin_amdgcn_global_load_lds((const __attribute__((address_space(1))) void*)(fr_ +  64), (__attribute__((address_space(3))) void*)(sl_ + 4096), 16, 0, 0); \
    __builtin_amdgcn_global_load_lds((const __attribute__((address_space(1))) void*)(fr_ +  80), (__attribute__((address_space(3))) void*)(sl_ + 5120), 16, 0, 0); \
    __builtin_amdgcn_global_load_lds((const __attribute__((address_space(1))) void*)(fr_ +  96), (__attribute__((address_space(3))) void*)(sl_ + 6144), 16, 0, 0); \
    __builtin_amdgcn_global_load_lds((const __attribute__((address_space(1))) void*)(fr_ + 112), (__attribute__((address_space(3))) void*)(sl_ + 7168), 16, 0, 0); }

  // ---- consumer state (waves 1-4): one 16-cout block each ----
  int ct = w - 1;
  int col = l & 15, kg = l >> 4;
  f32x4 acc[4] = {};   // 4 row-tiles of 16

#define CONSUME(K) { \
    const char* sl_ = &ldsA[(K) % 5][0]; \
    const u16* wk_ = Wt + ((K) << 12) + (((ct << 4) + col) << 6) + (kg << 3); \
    short8 b0_ = *(const short8*)(wk_); \
    short8 b1_ = *(const short8*)(wk_ + 32); \
    short8 a0_[4], a1_[4]; \
    _Pragma("unroll") for (int rt = 0; rt < 4; rt++) { \
      int row_ = (rt << 4) + col; \
      a0_[rt] = *(const short8*)(sl_ + (kg << 10) + (row_ << 4)); \
      a1_[rt] = *(const short8*)(sl_ + ((kg + 4) << 10) + (row_ << 4)); } \
    _Pragma("unroll") for (int rt = 0; rt < 4; rt++) { \
      acc[rt] = __builtin_amdgcn_mfma_f32_16x16x32_bf16(a0_[rt], b0_, acc[rt], 0, 0, 0); \
      acc[rt] = __builtin_amdgcn_mfma_f32_16x16x32_bf16(a1_[rt], b1_, acc[rt], 0, 0, 0); } }

  // batch j = GLD(j+3) [8 ops if j+3<27] + PROBE(j+6) [1 op if j+6<27];
  // before barrier@k retire through batch k-2, keep batches k-1,k:
#define NWAIT(K) ( (((K)-1) < 24 ? 8 : 0) + (((K)-1) < 21 ? 1 : 0) + \
                   (((K)     < 24) ? 8 : 0) + (((K)     < 21) ? 1 : 0) )

#define BODY(K) { \
    if (w == 0) { \
      if ((K) + 3 < 27) GLD((K) + 3) \
      if ((K) + 6 < 27) PROBE((K) + 6) \
      asm volatile("s_waitcnt vmcnt(%0)" :: "n"(NWAIT(K)) : "memory"); \
    } else { \
      CONSUME(K) \
    } \
    asm volatile("" ::: "memory"); \
    __builtin_amdgcn_s_barrier(); \
    asm volatile("" ::: "memory"); }

  // prologue: tile0 resident; batches -2 {GLD(1),P(4)}, -1 {GLD(2),P(5)} in flight
  if (w == 0) {
    PROBE(0) PROBE(1) PROBE(2) PROBE(3)
    asm volatile("s_waitcnt vmcnt(0)" ::: "memory");
    GLD(0)
    asm volatile("s_waitcnt vmcnt(0)" ::: "memory");
    PROBE(4) GLD(1) PROBE(5) GLD(2)
  }
  asm volatile("" ::: "memory");
  __builtin_amdgcn_s_barrier();
  asm volatile("" ::: "memory");

  BODY(0)  BODY(1)  BODY(2)  BODY(3)  BODY(4)  BODY(5)  BODY(6)
  BODY(7)  BODY(8)  BODY(9)  BODY(10) BODY(11) BODY(12) BODY(13)
  BODY(14) BODY(15) BODY(16) BODY(17) BODY(18) BODY(19) BODY(20)
  BODY(21) BODY(22) BODY(23) BODY(24) BODY(25) BODY(26)

#undef PROBE
#undef GLD
#undef CONSUME
#undef NWAIT
#undef BODY

  // epilogue (consumers): BN + ReLU, zeros for invalid (r >= U) rows
  if (w > 0) {
    int c = (ct << 4) | col;
    float al = ab[c], be = ab[64 + c];
#pragma unroll
    for (int rt = 0; rt < 4; rt++) {
#pragma unroll
      for (int i = 0; i < 4; i++) {
        int r = rbase + (rt << 4) + (kg << 2) + i;
        if (r >= NPTS) continue;
        bool valid = ((u32)r < U);
        float vv = 0.f;
        if (valid) {
          vv = fmaf(acc[rt][i], al, be);
          vv = vv > 0.f ? vv : 0.f;
        }
        out[((size_t)r << 6) + c] = vv;
      }
    }
  }
}

extern "C" void kernel_launch(void* const* d_in, const int* in_sizes, int n_in,
                              void* d_out, int out_size, void* d_ws, size_t ws_size,
                              hipStream_t stream) {
  const int*   coords = (const int*)d_in[0];
  const float* feats  = (const float*)d_in[1];
  const float* W      = (const float*)d_in[2];
  const float* bns    = (const float*)d_in[3];
  const float* bnb    = (const float*)d_in[4];
  const float* bnm    = (const float*)d_in[5];
  const float* bnv    = (const float*)d_in[6];
  float* out = (float*)d_out;

  char* ws = (char*)d_ws;
  size_t off = 0;
  auto alloc = [&](size_t bytes) -> void* {
    void* p = ws + off;
    off += (bytes + 255) & ~(size_t)255;
    return p;
  };
  u32* lut      = (u32*)alloc((size_t)(NKEYS + 1) * 4);  // +1 zero sentinel
  u32* partials = (u32*)alloc((NPART + 8) * 4);
  int* keys     = (int*)alloc((size_t)NPTS * 4);
  int* r2k      = (int*)alloc((size_t)NPTS * 4);
  u16* fdsb     = (u16*)alloc((size_t)(NPTS + 1) * 64 * 2);  // +1 zero row
  u16* Wt       = (u16*)alloc((size_t)27 * 4096 * 2);
  float* ab     = (float*)alloc(128 * 4);
  (void)ws_size; (void)out_size; (void)n_in; (void)in_sizes;

  float* fds32 = out;   // d_out doubles as f32 staging for multi-point voxels

  hipMemsetAsync(lut, 0, (size_t)(NKEYS + 1) * 4, stream);
  hipMemsetAsync(fdsb + (size_t)NPTS * 64, 0, 128, stream);   // zero row

  k0a_bn<<<1, 64, 0, stream>>>(bns, bnb, bnm, bnv, ab);
  k0b_wt<<<(27 * 4096 + 255) / 256, 256, 0, stream>>>(W, Wt);
  k1_keys<<<(NPTS + 255) / 256, 256, 0, stream>>>(coords, keys, lut);
  k2a_part<<<NPART, 256, 0, stream>>>(lut, partials);
  k2b_top<<<1, NPART, 0, stream>>>(partials);
  k2c_fill<<<NPART, 256, 0, stream>>>(lut, partials, r2k, fds32);
  k3_seg<<<(NPTS * 16 + 255) / 256, 256, 0, stream>>>(feats, keys, lut, fds32, fdsb);
  k3b_fix<<<(NPTS * 4 + 255) / 256, 256, 0, stream>>>(r2k, lut, partials + NPART, fds32, fdsb);
  // 64 rows per block; 9376 blocks (multiple of 8 for the XCD swizzle)
  k4_conv<<<(NPTS + 63) / 64, 320, 0, stream>>>(lut, r2k, fdsb, Wt,
                                                partials + NPART, ab, out);
}